// Round 1
// baseline (462.861 us; speedup 1.0000x reference)
//
#include <hip/hip_runtime.h>

#define DIM    256
#define NE     8192
#define NROWS  8192
#define DECAY  0.1f
#define EPS_F  1e-5f

// output offsets (floats), concat order: quantize_st, embed_ind, loss, embed_normalized, cluster_size_new, embed_avg_new
#define OUT_Q    0
#define OUT_IND  2097152
#define OUT_LOSS 2105344
#define OUT_NORM 2105345
#define OUT_CSN  4202497
#define OUT_AVG  4210689

// ws offsets (bytes): keys(u64[8192]) | ws_sum(f32[8192*256], transposed [j][d]) | bins(f32[8192]) | loss(f64) | S(f64) | enorm(f32[8192])
#define WS_KEYS  0
#define WS_SUM   65536
#define WS_BINS  8454144
#define WS_LOSS  8486912
#define WS_S     8486920
#define WS_ENORM 8486928
#define WS_ZERO_BYTES (WS_ENORM - WS_SUM)

__global__ __launch_bounds__(256) void vq_enorm_k(const float* __restrict__ E, float* __restrict__ enorm)
{
    const int j = blockIdx.x * blockDim.x + threadIdx.x;
    float s = 0.f;
    #pragma unroll 8
    for (int d = 0; d < DIM; ++d) {
        const float v = E[(size_t)d * NE + j];
        s += v * v;
    }
    enorm[j] = s;
}

__device__ __forceinline__ unsigned int f32_ord(float f)
{
    unsigned int u = __float_as_uint(f);
    return (u & 0x80000000u) ? ~u : (u | 0x80000000u);
}

#define BM 128
#define BN 128
#define BK 32

// dist[i][j] = enorm[j] - 2 * (x_i . e_j); per-row argmin via packed u64 atomicMin.
__global__ __launch_bounds__(256) void vq_dist_argmin_k(const float* __restrict__ X,
                                                        const float* __restrict__ E,
                                                        const float* __restrict__ enorm,
                                                        unsigned long long* __restrict__ keys)
{
    __shared__ float As[BK][BM + 4]; // k-major: As[k][r], stride 132 (16B aligned, low staging conflicts)
    __shared__ float Bs[BK][BN + 4]; // k-major: Bs[k][c]

    const int tid  = threadIdx.x;
    const int row0 = blockIdx.x * BM;
    const int col0 = blockIdx.y * BN;
    const int tx   = tid & 15;
    const int ty   = tid >> 4;

    float acc[8][8];
    #pragma unroll
    for (int i = 0; i < 8; ++i)
        #pragma unroll
        for (int j = 0; j < 8; ++j) acc[i][j] = 0.f;

    for (int k0 = 0; k0 < DIM; k0 += BK) {
        // stage A: 128 rows x 32 k (transposed into k-major)
        #pragma unroll
        for (int p = 0; p < 4; ++p) {
            const int r  = (tid >> 3) + p * 32;
            const int kk = (tid & 7) * 4;
            const float4 v = *(const float4*)(X + (size_t)(row0 + r) * DIM + k0 + kk);
            As[kk + 0][r] = v.x;
            As[kk + 1][r] = v.y;
            As[kk + 2][r] = v.z;
            As[kk + 3][r] = v.w;
        }
        // stage B: 32 k x 128 cols (natural layout)
        #pragma unroll
        for (int p = 0; p < 4; ++p) {
            const int kk = (tid >> 5) + p * 8;
            const int c  = (tid & 31) * 4;
            const float4 v = *(const float4*)(E + (size_t)(k0 + kk) * NE + col0 + c);
            *(float4*)&Bs[kk][c] = v;
        }
        __syncthreads();
        #pragma unroll 4
        for (int k = 0; k < BK; ++k) {
            // split 4+4 fragments: each b128 read covers 64 consecutive floats across 16 lanes -> conflict-free
            const float4 a0 = *(const float4*)&As[k][ty * 4];
            const float4 a1 = *(const float4*)&As[k][64 + ty * 4];
            const float4 b0 = *(const float4*)&Bs[k][tx * 4];
            const float4 b1 = *(const float4*)&Bs[k][64 + tx * 4];
            const float a[8] = {a0.x, a0.y, a0.z, a0.w, a1.x, a1.y, a1.z, a1.w};
            const float b[8] = {b0.x, b0.y, b0.z, b0.w, b1.x, b1.y, b1.z, b1.w};
            #pragma unroll
            for (int i = 0; i < 8; ++i)
                #pragma unroll
                for (int j = 0; j < 8; ++j)
                    acc[i][j] += a[i] * b[j];
        }
        __syncthreads();
    }

    // epilogue: per-row argmin over this block's 128 cols, then global combine
    float en[8];
    #pragma unroll
    for (int j = 0; j < 8; ++j) {
        const int c = col0 + ((j < 4) ? (tx * 4 + j) : (64 + tx * 4 + (j - 4)));
        en[j] = enorm[c];
    }
    #pragma unroll
    for (int i = 0; i < 8; ++i) {
        const int row = row0 + ((i < 4) ? (ty * 4 + i) : (64 + ty * 4 + (i - 4)));
        float best = 0.f;
        int   bi   = -1;
        #pragma unroll
        for (int j = 0; j < 8; ++j) { // ascending col order -> first-min tie-break
            const int c = col0 + ((j < 4) ? (tx * 4 + j) : (64 + tx * 4 + (j - 4)));
            const float d = en[j] - 2.f * acc[i][j];
            if (bi < 0 || d < best) { best = d; bi = c; }
        }
        unsigned long long key = ((unsigned long long)f32_ord(best) << 32) | (unsigned int)bi;
        #pragma unroll
        for (int off = 1; off < 16; off <<= 1) { // reduce across the 16 tx lanes sharing these rows
            const unsigned long long o = __shfl_xor(key, off);
            if (o < key) key = o;
        }
        if (tx == 0) atomicMin(&keys[row], key);
    }
}

// per-row: gather code vector, write quantize_st + ind, accumulate loss, bins, segment sums (transposed, coalesced atomics)
__global__ __launch_bounds__(256) void vq_gather_stats_k(const float* __restrict__ X,
                                                         const float* __restrict__ E,
                                                         const unsigned long long* __restrict__ keys,
                                                         float* __restrict__ out_q,
                                                         float* __restrict__ out_ind,
                                                         float* __restrict__ ws_sum,
                                                         float* __restrict__ bins,
                                                         double* __restrict__ loss)
{
    const int tid = threadIdx.x;
    float lsum = 0.f;
    #pragma unroll
    for (int q = 0; q < 4; ++q) {
        const int row = blockIdx.x * 4 + q;
        const int j   = (int)(keys[row] & 0xffffffffull);
        const float x  = X[(size_t)row * DIM + tid];
        const float qv = E[(size_t)tid * NE + j];
        out_q[(size_t)row * DIM + tid] = x + (qv - x); // mimic reference rounding exactly
        const float d = qv - x;
        lsum += d * d;
        atomicAdd(&ws_sum[(size_t)j * DIM + tid], x);
        if (tid == 0) {
            atomicAdd(&bins[j], 1.0f);
            out_ind[row] = (float)j;
        }
    }
    #pragma unroll
    for (int off = 32; off > 0; off >>= 1) lsum += __shfl_down(lsum, off);
    __shared__ double wred[4];
    if ((tid & 63) == 0) wred[tid >> 6] = (double)lsum;
    __syncthreads();
    if (tid == 0) atomicAdd(loss, wred[0] + wred[1] + wred[2] + wred[3]);
}

__global__ __launch_bounds__(256) void vq_csn_k(const float* __restrict__ cs,
                                                const float* __restrict__ bins,
                                                float* __restrict__ out_csn,
                                                float* __restrict__ out_loss,
                                                const double* __restrict__ loss,
                                                double* __restrict__ S)
{
    const int tid = threadIdx.x;
    const int i = blockIdx.x * 256 + tid;
    const float csn = cs[i] * DECAY + (1.0f - DECAY) * bins[i];
    out_csn[i] = csn;
    double v = (double)csn;
    #pragma unroll
    for (int off = 32; off > 0; off >>= 1) v += __shfl_down(v, off);
    __shared__ double wred[4];
    if ((tid & 63) == 0) wred[tid >> 6] = v;
    __syncthreads();
    if (tid == 0) atomicAdd(S, wred[0] + wred[1] + wred[2] + wred[3]);
    if (blockIdx.x == 0 && tid == 0) out_loss[0] = (float)(loss[0] * (1.0 / 2097152.0));
}

// tile-transpose ws_sum [j][d] -> [d][j] outputs; fuse EMA + normalize
__global__ __launch_bounds__(256) void vq_embed_k(const float* __restrict__ EA,
                                                  const float* __restrict__ cs,
                                                  const float* __restrict__ bins,
                                                  const float* __restrict__ ws_sum,
                                                  const double* __restrict__ Sp,
                                                  float* __restrict__ out_norm,
                                                  float* __restrict__ out_avg)
{
    __shared__ float T[64][69]; // stride 69: 5*jc mod 32 -> 2-way banks (free)
    const int tid = threadIdx.x;
    const int j0 = blockIdx.x * 64;
    const int d0 = blockIdx.y * 64;
    #pragma unroll
    for (int p = 0; p < 4; ++p) {
        const int jr = (tid >> 4) + p * 16;
        const int dc = (tid & 15) * 4;
        const float4 v = *(const float4*)(ws_sum + (size_t)(j0 + jr) * DIM + d0 + dc);
        T[jr][dc + 0] = v.x; T[jr][dc + 1] = v.y; T[jr][dc + 2] = v.z; T[jr][dc + 3] = v.w;
    }
    __syncthreads();
    const double S = Sp[0];
    const float fac = (float)(S / (S + (double)NE * 1e-5));
    const int jc = tid & 63;
    const int j  = j0 + jc;
    const float csn  = cs[j] * DECAY + (1.0f - DECAY) * bins[j];
    const float cs_j = (csn + EPS_F) * fac;
    const int drb = (tid >> 6) * 16;
    #pragma unroll
    for (int p = 0; p < 16; ++p) {
        const int dr = drb + p;
        const float sum = T[jc][dr];
        const float ea  = EA[(size_t)(d0 + dr) * NE + j];
        const float ean = DECAY * ea + (1.0f - DECAY) * sum;
        out_avg[(size_t)(d0 + dr) * NE + j]  = ean;
        out_norm[(size_t)(d0 + dr) * NE + j] = ean / cs_j;
    }
}

extern "C" void kernel_launch(void* const* d_in, const int* in_sizes, int n_in,
                              void* d_out, int out_size, void* d_ws, size_t ws_size,
                              hipStream_t stream)
{
    const float* X  = (const float*)d_in[0]; // [8192][256]
    const float* E  = (const float*)d_in[1]; // [256][8192]
    const float* CS = (const float*)d_in[2]; // [8192]
    const float* EA = (const float*)d_in[3]; // [256][8192]
    float* out = (float*)d_out;
    char*  ws  = (char*)d_ws;

    unsigned long long* keys = (unsigned long long*)(ws + WS_KEYS);
    float*  ws_sum = (float*)(ws + WS_SUM);
    float*  bins   = (float*)(ws + WS_BINS);
    double* loss   = (double*)(ws + WS_LOSS);
    double* S      = (double*)(ws + WS_S);
    float*  enorm  = (float*)(ws + WS_ENORM);

    hipMemsetAsync(keys, 0xFF, (size_t)NROWS * sizeof(unsigned long long), stream); // u64 max
    hipMemsetAsync(ws + WS_SUM, 0, (size_t)WS_ZERO_BYTES, stream);                  // sums, bins, loss, S

    vq_enorm_k<<<NE / 256, 256, 0, stream>>>(E, enorm);
    vq_dist_argmin_k<<<dim3(NROWS / BM, NE / BN), 256, 0, stream>>>(X, E, enorm, keys);
    vq_gather_stats_k<<<NROWS / 4, 256, 0, stream>>>(X, E, keys, out + OUT_Q, out + OUT_IND, ws_sum, bins, loss);
    vq_csn_k<<<NE / 256, 256, 0, stream>>>(CS, bins, out + OUT_CSN, out + OUT_LOSS, loss, S);
    vq_embed_k<<<dim3(NE / 64, DIM / 64), 256, 0, stream>>>(EA, CS, bins, ws_sum, S, out + OUT_NORM, out + OUT_AVG);
}